// Round 9
// baseline (206.890 us; speedup 1.0000x reference)
//
#include <hip/hip_runtime.h>
#include <stdint.h>

#define H_ 96
#define W_ 96
#define C_ 256
#define O_ 256
#define N_ 2
#define HW_ (H_*W_)          // 9216
#define M_ (N_*HW_)          // 18432
#define GK 2304              // C_*9
#define NKC 36               // GK/64 chunks

typedef __bf16 bf16x8 __attribute__((ext_vector_type(8)));
typedef float f32x4 __attribute__((ext_vector_type(4)));
typedef unsigned short us4 __attribute__((ext_vector_type(4)));

__device__ __forceinline__ unsigned short f2bf(float f) {
  union { float f; unsigned int u; } v; v.f = f;
  unsigned int u = v.u;
  return (unsigned short)((u + 0x7fffu + ((u >> 16) & 1u)) >> 16);
}
__device__ __forceinline__ float bf2f(unsigned short h) {
  union { unsigned int u; float f; } v; v.u = ((unsigned int)h) << 16;
  return v.f;
}

// ---------------- Kernel 1: combined prep.
//  blocks [0,1152):     NCHW fp32 -> NHWC bf16 transpose, 64p x 64c tiles.
//                       16.6KB LDS -> full occupancy (memory kernel needs waves).
//                       LDS stride 65: phase-1 scalar stores and phase-2 reads
//                       both 2-way (free per m136).
//  blocks [1152,1408):  Wp[o][t*256+c] = bf16(w_deform[o][c][t]), one o/block
//  blocks [1408,1552):  w6p[t][j][c] (j<6 real, 6..15 zero)
__global__ __launch_bounds__(256) void k_pre(const float* __restrict__ x,
                                             const float* __restrict__ w_df,
                                             const float* __restrict__ w_tm,
                                             const float* __restrict__ w_tr,
                                             unsigned short* __restrict__ xt,
                                             unsigned short* __restrict__ wp,
                                             unsigned short* __restrict__ w6p) {
  const int b = blockIdx.x;
  const int tid = threadIdx.x;
  if (b < 1152) {
    __shared__ float tile[64][65];
    const int pt = b % 144;          // 144 p-tiles of 64
    const int ct = (b / 144) & 3;    // 4 c-tiles of 64
    const int n  = b / 576;
    const int p0 = pt * 64, c0 = ct * 64;
    const float* xp = x + (size_t)n * C_ * HW_;
    unsigned short* xtp = xt + (size_t)n * C_ * HW_;
    const int tx = tid & 15, ty = tid >> 4;  // 16 lanes x 16 c-rows
#pragma unroll
    for (int pass = 0; pass < 4; pass++) {
      const int c = pass * 16 + ty;
      const f32x4 v = *(const f32x4*)(xp + (size_t)(c0 + c) * HW_ + p0 + tx * 4);
#pragma unroll
      for (int i = 0; i < 4; i++) tile[c][tx * 4 + i] = v[i];
    }
    __syncthreads();
    const int cg = tid & 15, pr = tid >> 4;
#pragma unroll
    for (int pass = 0; pass < 4; pass++) {
      const int p = pass * 16 + pr;
      us4 v;
#pragma unroll
      for (int i = 0; i < 4; i++) v[i] = f2bf(tile[cg * 4 + i][p]);
      *(us4*)(xtp + (size_t)(p0 + p) * C_ + c0 + cg * 4) = v;
    }
  } else if (b < 1408) {
    __shared__ float lds[9][258];
    const int o = b - 1152;
    const float* src = w_df + (size_t)o * GK;
#pragma unroll
    for (int i = 0; i < 9; i++) {
      int e = tid + i * 256;           // e = c*9 + t
      int c = e / 9, t = e - c * 9;
      lds[t][c] = src[e];
    }
    __syncthreads();
    unsigned short* dst = wp + (size_t)o * GK;
#pragma unroll
    for (int i = 0; i < 9; i++) {
      int j = tid + i * 256;           // j = t*256 + c
      dst[j] = f2bf(lds[j >> 8][j & 255]);
    }
  } else {
    int idx = (b - 1408) * 256 + tid;  // < 9*16*256 = 36864
    int t = idx >> 12;
    int r = idx & 4095;
    int j = r >> 8;
    int c = r & 255;
    float v = 0.f;
    if (j < 4) v = w_tm[(size_t)(j * C_ + c) * 9 + t];
    else if (j < 6) v = w_tr[(size_t)((j - 4) * C_ + c) * 9 + t];
    w6p[idx] = f2bf(v);
  }
}

// ---------------- Kernel 2: FUSED offsets + sample + GEMM + BN + res + ReLU.
// Block: 64m x 256o, 512 threads / 8 waves (wave-tile 32m x 64o). Grid 288
// (36/XCD band swizzle). B-feed halves vs 32m tile: chip B L2-stream
// 1.3GB -> 648MB (the r8 bottleneck). Single-buffer 50KB LDS ->
// 2 blocks/CU. STAGE_B issued before A lerp so DMA lands under VALU work;
// corner loads for kc+1 register-prefetched before MFMA(kc).
__global__ __launch_bounds__(512, 4) void k_fused(const unsigned short* __restrict__ xt,
                                                  const unsigned short* __restrict__ Wp,
                                                  const unsigned short* __restrict__ w6p,
                                                  const float* __restrict__ b_tm,
                                                  const float* __restrict__ b_tr,
                                                  const float* __restrict__ xres,
                                                  const float* __restrict__ gamma,
                                                  const float* __restrict__ beta,
                                                  const float* __restrict__ mean,
                                                  const float* __restrict__ var,
                                                  float* __restrict__ out) {
  __shared__ unsigned short As[64 * 64] __attribute__((aligned(16)));   //  8 KB
  __shared__ unsigned short Bs[256 * 64] __attribute__((aligned(16)));  // 32 KB
  __shared__ float sred[8][16][8];
  __shared__ float coords_s[64][9][2];
  const int tid = threadIdx.x;
  const int wave = tid >> 6, lane = tid & 63;
  const int row = lane & 15, quad = lane >> 4;
  const int wm = wave & 1, wo = wave >> 1;  // 32-m half, 64-o quarter
  const int bm = (blockIdx.x & 7) * 36 + (blockIdx.x >> 3);  // XCD m-band swizzle
  const int m0 = bm * 64;
  const int n = m0 / HW_;   // 64 | 9216: tile never crosses n
  const int sr = tid >> 4;  // staging row 0..31 (+32 on pass 1)
  const int cg = tid & 15;  // staging 4-channel group
  const int coff = cg * 4;

  // ---- Prologue: offset conv, 8 waves = 4 strips x 2 K-halves ----
  {
    const int strip = wave & 3, khalf = wave >> 2;
    const int m0w = m0 + strip * 16;
    const int hw0 = m0w - n * HW_;
    const int h = hw0 / W_;
    const int w0 = hw0 - h * W_;  // multiple of 16
    f32x4 oacc = {0.f, 0.f, 0.f, 0.f};
    const bf16x8 zero8 = {};
#pragma unroll
    for (int t = 0; t < 9; t++) {
      const int ty = t / 3, tx = t % 3;
      const int y = h + ty - 1;
      if (y < 0 || y >= H_) continue;  // wave-uniform
      const int xx = w0 + row + tx - 1;
      const bool valid = (xx >= 0) && (xx < W_);
      const int xc = min(max(xx, 0), W_ - 1);
      const unsigned short* arow =
          xt + (size_t)((n * H_ + y) * W_ + xc) * C_ + khalf * 128 + quad * 8;
      const unsigned short* brow =
          w6p + (size_t)(t * 16 + row) * C_ + khalf * 128 + quad * 8;
#pragma unroll
      for (int ks = 0; ks < 4; ks++) {
        bf16x8 av = *(const bf16x8*)(const void*)(arow + ks * 32);
        if (!valid) av = zero8;
        bf16x8 bv = *(const bf16x8*)(const void*)(brow + ks * 32);
        oacc = __builtin_amdgcn_mfma_f32_16x16x32_bf16(av, bv, oacc, 0, 0, 0);
      }
    }
    if (row < 6) {
#pragma unroll
      for (int r = 0; r < 4; r++) sred[wave][quad * 4 + r][row] = oacc[r];
    }
  }
  __syncthreads();
  if (wave < 4 && lane < 16) {
    const int r = wave * 16 + lane;
    const int hwm = m0 + r - n * HW_;
    const int h = hwm / W_, w = hwm - h * W_;
    float a[6];
#pragma unroll
    for (int j = 0; j < 6; j++) a[j] = sred[wave][lane][j] + sred[wave + 4][lane][j];
    const float tm0 = a[0] + b_tm[0];
    const float tm1 = a[1] + b_tm[1];
    const float tm2 = a[2] + b_tm[2];
    const float tm3 = a[3] + b_tm[3];
    const float tr0 = a[4] + b_tr[0];
    const float tr1 = a[5] + b_tr[1];
#pragma unroll
    for (int t = 0; t < 9; t++) {
      const float ry = (float)(t / 3) - 1.f;
      const float rx = (float)(t % 3) - 1.f;
      coords_s[r][t][0] = (float)h + tr0 + tm0 * ry + tm1 * rx;
      coords_s[r][t][1] = (float)w + tr1 + tm2 * ry + tm3 * rx;
    }
  }
  __syncthreads();

  // ---- Main loop ----
  f32x4 acc[2][4] = {};
  float cw[2][4];   // bilinear weights (validity folded), rows sr / sr+32
  int cbase[2][4];  // clamped corner element-offsets into xt
  us4 u[2][4];      // register-prefetched corner data

#define PREP(KC)                                                               \
  {                                                                            \
    const int tap = (KC) >> 2;                                                 \
    _Pragma("unroll") for (int pass = 0; pass < 2; pass++) {                   \
      const int r = pass * 32 + sr;                                            \
      const float py = coords_s[r][tap][0];                                    \
      const float px = coords_s[r][tap][1];                                    \
      const float fy = floorf(py), fx = floorf(px);                            \
      const float wy = py - fy, wx = px - fx;                                  \
      const int y0 = (int)fy, x0 = (int)fx;                                    \
      const int y1 = y0 + 1, x1 = x0 + 1;                                      \
      const float vy0 = (y0 >= 0 && y0 < H_) ? 1.f : 0.f;                      \
      const float vy1 = (y1 >= 0 && y1 < H_) ? 1.f : 0.f;                      \
      const float vx0 = (x0 >= 0 && x0 < W_) ? 1.f : 0.f;                      \
      const float vx1 = (x1 >= 0 && x1 < W_) ? 1.f : 0.f;                      \
      cw[pass][0] = (1.f - wy) * (1.f - wx) * vy0 * vx0;                       \
      cw[pass][1] = (1.f - wy) * wx * vy0 * vx1;                               \
      cw[pass][2] = wy * (1.f - wx) * vy1 * vx0;                               \
      cw[pass][3] = wy * wx * vy1 * vx1;                                       \
      const int cy0 = min(max(y0, 0), H_ - 1), cy1 = min(max(y1, 0), H_ - 1);  \
      const int cx0 = min(max(x0, 0), W_ - 1), cx1 = min(max(x1, 0), W_ - 1);  \
      cbase[pass][0] = ((n * H_ + cy0) * W_ + cx0) * C_;                       \
      cbase[pass][1] = ((n * H_ + cy0) * W_ + cx1) * C_;                       \
      cbase[pass][2] = ((n * H_ + cy1) * W_ + cx0) * C_;                       \
      cbase[pass][3] = ((n * H_ + cy1) * W_ + cx1) * C_;                       \
    }                                                                          \
  }

#define LOAD_CORNERS(KC)                                                       \
  {                                                                            \
    const int c4 = ((KC) & 3) * 64 + coff;                                     \
    _Pragma("unroll") for (int pass = 0; pass < 2; pass++)                     \
        _Pragma("unroll") for (int i = 0; i < 4; i++)                          \
            u[pass][i] = *(const us4*)(xt + cbase[pass][i] + c4);              \
  }

#define WRITE_A()                                                              \
  {                                                                            \
    _Pragma("unroll") for (int pass = 0; pass < 2; pass++) {                   \
      const int r = pass * 32 + sr;                                            \
      us4 res;                                                                 \
      _Pragma("unroll") for (int i = 0; i < 4; i++) {                          \
        float v = cw[pass][0] * bf2f(u[pass][0][i]) +                          \
                  cw[pass][1] * bf2f(u[pass][1][i]) +                          \
                  cw[pass][2] * bf2f(u[pass][2][i]) +                          \
                  cw[pass][3] * bf2f(u[pass][3][i]);                           \
        res[i] = f2bf(v);                                                      \
      }                                                                        \
      *(us4*)(void*)&As[r * 64 + (((cg >> 1) ^ (r & 7)) << 3) + ((cg & 1) << 2)] = res; \
    }                                                                          \
  }

#define STAGE_B(KC)                                                            \
  {                                                                            \
    const int k0 = (KC) * 64;                                                  \
    _Pragma("unroll") for (int i = 0; i < 4; i++) {                            \
      int g = i * 512 + tid;                                                   \
      int rr = g >> 3, j = g & 7;                                              \
      int gc = j ^ (rr & 7);                                                   \
      __builtin_amdgcn_global_load_lds(                                        \
          (const __attribute__((address_space(1))) void*)(Wp + (size_t)rr * GK + k0 + gc * 8), \
          (__attribute__((address_space(3))) void*)(&Bs[(size_t)g * 8]),       \
          16, 0, 0);                                                           \
    }                                                                          \
  }

  PREP(0);
  LOAD_CORNERS(0);
  for (int kc = 0; kc < NKC; kc++) {
    STAGE_B(kc);   // DMA first: lands under the lerp/ds_write VALU below
    WRITE_A();
    __syncthreads();
    if (kc + 1 < NKC) {
      if (((kc + 1) & 3) == 0) PREP(kc + 1);
      LOAD_CORNERS(kc + 1);  // latency overlaps MFMA phase below
    }
#pragma unroll
    for (int ks = 0; ks < 64; ks += 32) {
      const int cbk = ks >> 3;
      bf16x8 av[2];
#pragma unroll
      for (int mt = 0; mt < 2; mt++) {
        const int ra = wm * 32 + mt * 16 + row;
        av[mt] = *(const bf16x8*)(const void*)&As[ra * 64 + (((cbk + quad) ^ (ra & 7)) << 3)];
      }
#pragma unroll
      for (int ot = 0; ot < 4; ot++) {
        const int rb = wo * 64 + ot * 16 + row;
        bf16x8 bv = *(const bf16x8*)(const void*)&Bs[rb * 64 + (((cbk + quad) ^ (rb & 7)) << 3)];
#pragma unroll
        for (int mt = 0; mt < 2; mt++)
          acc[mt][ot] = __builtin_amdgcn_mfma_f32_16x16x32_bf16(av[mt], bv, acc[mt][ot], 0, 0, 0);
      }
    }
    __syncthreads();
  }

  // ---- Epilogue: BN + residual + ReLU, float4 rows ----
#pragma unroll
  for (int ot = 0; ot < 4; ot++) {
    const int o = wo * 64 + ot * 16 + row;
    const float sc = rsqrtf(var[o] + 1e-5f) * gamma[o];
    const float bi = beta[o] - mean[o] * sc;
#pragma unroll
    for (int mt = 0; mt < 2; mt++) {
      const int hwb = m0 - n * HW_ + wm * 32 + mt * 16 + quad * 4;
      const size_t obase = (size_t)(n * O_ + o) * HW_ + hwb;
      const f32x4 rv = *(const f32x4*)(xres + obase);
      f32x4 ov;
#pragma unroll
      for (int r = 0; r < 4; r++) ov[r] = fmaxf(acc[mt][ot][r] * sc + bi + rv[r], 0.f);
      *(f32x4*)(out + obase) = ov;
    }
  }
}

extern "C" void kernel_launch(void* const* d_in, const int* in_sizes, int n_in,
                              void* d_out, int out_size, void* d_ws, size_t ws_size,
                              hipStream_t stream) {
  const float* x     = (const float*)d_in[0];
  const float* w_tm  = (const float*)d_in[2];
  const float* b_tm  = (const float*)d_in[3];
  const float* w_tr  = (const float*)d_in[4];
  const float* b_tr  = (const float*)d_in[5];
  const float* w_df  = (const float*)d_in[6];
  const float* gamma = (const float*)d_in[7];
  const float* beta  = (const float*)d_in[8];
  const float* mean  = (const float*)d_in[9];
  const float* var   = (const float*)d_in[10];
  float* out = (float*)d_out;

  char* ws = (char*)d_ws;
  unsigned short* xt  = (unsigned short*)(ws);                       //  9,437,184 B
  unsigned short* WpB = (unsigned short*)(ws + 9437184);             //  1,179,648 B
  unsigned short* w6p = (unsigned short*)(ws + 9437184 + 1179648);   //     73,728 B

  k_pre<<<1552, 256, 0, stream>>>(x, w_df, w_tm, w_tr, xt, WpB, w6p);
  k_fused<<<288, 512, 0, stream>>>(xt, WpB, w6p, b_tm, b_tr, x,
                                   gamma, beta, mean, var, out);
}

// Round 10
// 188.150 us; speedup vs baseline: 1.0996x; 1.0996x over previous
//
#include <hip/hip_runtime.h>
#include <stdint.h>

#define H_ 96
#define W_ 96
#define C_ 256
#define O_ 256
#define N_ 2
#define HW_ (H_*W_)          // 9216
#define M_ (N_*HW_)          // 18432
#define GK 2304              // C_*9

typedef __bf16 bf16x8 __attribute__((ext_vector_type(8)));
typedef float f32x4 __attribute__((ext_vector_type(4)));
typedef unsigned short us4 __attribute__((ext_vector_type(4)));
typedef unsigned short us8 __attribute__((ext_vector_type(8)));

__device__ __forceinline__ unsigned short f2bf(float f) {
  union { float f; unsigned int u; } v; v.f = f;
  unsigned int u = v.u;
  return (unsigned short)((u + 0x7fffu + ((u >> 16) & 1u)) >> 16);
}
__device__ __forceinline__ float bf2f(unsigned short h) {
  union { unsigned int u; float f; } v; v.u = ((unsigned int)h) << 16;
  return v.f;
}

// ---------------- Kernel 1: combined prep.
//  blocks [0,288):    NCHW fp32 -> NHWC bf16 transpose, 128p x 128c tiles.
//                     Reads 512B granules, writes 256B granules (both sides
//                     >=256B for the first time; prior variants all had a
//                     <=256B strided side -> ~1.2TB/s).
//  blocks [288,576):  Wfrag pack: B in MFMA-fragment order so k_fused's bv
//                     load is one fully-coalesced 1KB global_load per wave.
//                     Wfrag[(((t*8+ks)*16+g)*64+l)*8+j] = w_df[o][c][t],
//                     o=g*16+(l&15), c=ks*32+(l>>4)*8+j.
//  blocks [576,720):  w6p[t][j][c] (j<6 real, 6..15 zero)
__global__ __launch_bounds__(256) void k_pre(const float* __restrict__ x,
                                             const float* __restrict__ w_df,
                                             const float* __restrict__ w_tm,
                                             const float* __restrict__ w_tr,
                                             unsigned short* __restrict__ xt,
                                             unsigned short* __restrict__ wfrag,
                                             unsigned short* __restrict__ w6p) {
  const int b = blockIdx.x;
  const int tid = threadIdx.x;
  if (b < 288) {
    __shared__ unsigned short tile[128][130];
    const int pt = b % 72;          // 72 p-tiles of 128
    const int ch = (b / 72) & 1;    // 2 c-halves of 128
    const int n  = b / 144;
    const int p0 = pt * 128, c0 = ch * 128;
    const float* xp = x + (size_t)n * C_ * HW_;
    unsigned short* xtp = xt + (size_t)n * C_ * HW_;
    const int tx = tid & 31, ty = tid >> 5;  // 32 p-chunks x 8 c-rows
#pragma unroll
    for (int pass = 0; pass < 16; pass++) {
      const int c = pass * 8 + ty;
      const f32x4 v = *(const f32x4*)(xp + (size_t)(c0 + c) * HW_ + p0 + tx * 4);
#pragma unroll
      for (int i = 0; i < 4; i++) tile[tx * 4 + i][c] = f2bf(v[i]);
    }
    __syncthreads();
    const int wave = tid >> 6, lane = tid & 63;
    const int l32 = lane & 31, ph = lane >> 5;
#pragma unroll
    for (int pass = 0; pass < 16; pass++) {
      const int p = pass * 8 + wave * 2 + ph;
      us4 v;
#pragma unroll
      for (int i = 0; i < 4; i++) v[i] = tile[p][l32 * 4 + i];
      *(us4*)(xtp + (size_t)(p0 + p) * C_ + c0 + l32 * 4) = v;
    }
  } else if (b < 576) {
    const int base = (b - 288) * 2048 + tid * 8;  // < 589824
    const int l  = (base >> 3) & 63;
    const int g  = (base >> 9) & 15;
    const int ks = (base >> 13) & 7;
    const int t  = base >> 16;
    const int o  = g * 16 + (l & 15);
    const int c  = ks * 32 + (l >> 4) * 8;
    us8 res;
#pragma unroll
    for (int j = 0; j < 8; j++) res[j] = f2bf(w_df[(size_t)(o * 256 + c + j) * 9 + t]);
    *(us8*)(wfrag + base) = res;
  } else {
    int idx = (b - 576) * 256 + tid;   // < 9*16*256 = 36864
    int t = idx >> 12;
    int r = idx & 4095;
    int j = r >> 8;
    int c = r & 255;
    float v = 0.f;
    if (j < 4) v = w_tm[(size_t)(j * C_ + c) * 9 + t];
    else if (j < 6) v = w_tr[(size_t)((j - 4) * C_ + c) * 9 + t];
    w6p[idx] = f2bf(v);
  }
}

// ---------------- Kernel 2: FUSED offsets + sample + GEMM + BN + res + ReLU.
// Block: 16m x 256o, 4 waves (wave-tile 16m x 64o). Grid 1152, XCD m-band
// swizzle, ~19KB LDS + launch_bounds(256,4) -> 4 blocks/CU co-resident.
// Iteration = ONE TAP (BK=256): lerp 16m x 256ch into double-buffered As,
// ONE lgkm barrier, then 8 ks-steps of MFMA. B comes straight from global
// Wfrag (fragment-order, 1KB coalesced per wave-load, L2-resident) -- no
// B-DMA, no vmcnt(0) drain at the barrier. 9 barriers total (was 72).
__global__ __launch_bounds__(256, 4) void k_fused(const unsigned short* __restrict__ xt,
                                                  const unsigned short* __restrict__ Wfrag,
                                                  const unsigned short* __restrict__ w6p,
                                                  const float* __restrict__ b_tm,
                                                  const float* __restrict__ b_tr,
                                                  const float* __restrict__ xres,
                                                  const float* __restrict__ gamma,
                                                  const float* __restrict__ beta,
                                                  const float* __restrict__ mean,
                                                  const float* __restrict__ var,
                                                  float* __restrict__ out) {
  __shared__ unsigned short As[2][16 * 256] __attribute__((aligned(16)));  // 16KB
  __shared__ float sred[4][16][8];
  __shared__ float coords_s[16][9][2];
  const int tid = threadIdx.x;
  const int wave = tid >> 6, lane = tid & 63;
  const int row = lane & 15, quad = lane >> 4;
  const int bm = (blockIdx.x & 7) * 144 + (blockIdx.x >> 3);  // XCD m-band swizzle
  const int m0 = bm * 16;
  const int n = m0 / HW_;   // 16 | 9216: tile never crosses n
  const int sr = tid >> 4;  // staging row 0..15
  const int cg = tid & 15;  // staging 16-channel group

  // ---- Prologue: offset conv for the 16-m strip; 4 waves split K ----
  {
    const int hw0 = m0 - n * HW_;
    const int h = hw0 / W_;
    const int w0 = hw0 - h * W_;  // multiple of 16
    const int cq = wave * 64;     // this wave's 64-channel quarter
    f32x4 oacc = {0.f, 0.f, 0.f, 0.f};
    const bf16x8 zero8 = {};
#pragma unroll
    for (int t = 0; t < 9; t++) {
      const int ty = t / 3, tx = t % 3;
      const int y = h + ty - 1;
      if (y < 0 || y >= H_) continue;  // wave-uniform
      const int xx = w0 + row + tx - 1;
      const bool valid = (xx >= 0) && (xx < W_);
      const int xc = min(max(xx, 0), W_ - 1);
      const unsigned short* arow =
          xt + (size_t)((n * H_ + y) * W_ + xc) * C_ + cq + quad * 8;
      const unsigned short* brow =
          w6p + (size_t)(t * 16 + row) * C_ + cq + quad * 8;
#pragma unroll
      for (int ks = 0; ks < 2; ks++) {
        bf16x8 av = *(const bf16x8*)(const void*)(arow + ks * 32);
        if (!valid) av = zero8;
        bf16x8 bv = *(const bf16x8*)(const void*)(brow + ks * 32);
        oacc = __builtin_amdgcn_mfma_f32_16x16x32_bf16(av, bv, oacc, 0, 0, 0);
      }
    }
    if (row < 6) {
#pragma unroll
      for (int r = 0; r < 4; r++) sred[wave][quad * 4 + r][row] = oacc[r];
    }
  }
  __syncthreads();
  if (wave == 0 && lane < 16) {
    const int hwm = m0 + lane - n * HW_;
    const int h = hwm / W_, w = hwm - h * W_;
    float a[6];
#pragma unroll
    for (int j = 0; j < 6; j++)
      a[j] = sred[0][lane][j] + sred[1][lane][j] + sred[2][lane][j] + sred[3][lane][j];
    const float tm0 = a[0] + b_tm[0];
    const float tm1 = a[1] + b_tm[1];
    const float tm2 = a[2] + b_tm[2];
    const float tm3 = a[3] + b_tm[3];
    const float tr0 = a[4] + b_tr[0];
    const float tr1 = a[5] + b_tr[1];
#pragma unroll
    for (int t = 0; t < 9; t++) {
      const float ry = (float)(t / 3) - 1.f;
      const float rx = (float)(t % 3) - 1.f;
      coords_s[lane][t][0] = (float)h + tr0 + tm0 * ry + tm1 * rx;
      coords_s[lane][t][1] = (float)w + tr1 + tm2 * ry + tm3 * rx;
    }
  }
  __syncthreads();

  // ---- Main loop over 9 taps ----
  f32x4 acc[4] = {};
  float cw0, cw1, cw2, cw3;
  int cb0, cb1, cb2, cb3;
  us8 u0[4], u1[4];  // corner data, channels cg*16..+7 and +8..+15

#define PREP(TAP)                                                              \
  {                                                                            \
    const float py = coords_s[sr][TAP][0];                                     \
    const float px = coords_s[sr][TAP][1];                                     \
    const float fy = floorf(py), fx = floorf(px);                              \
    const float wy = py - fy, wx = px - fx;                                    \
    const int y0 = (int)fy, x0 = (int)fx;                                      \
    const int y1 = y0 + 1, x1 = x0 + 1;                                        \
    const float vy0 = (y0 >= 0 && y0 < H_) ? 1.f : 0.f;                        \
    const float vy1 = (y1 >= 0 && y1 < H_) ? 1.f : 0.f;                        \
    const float vx0 = (x0 >= 0 && x0 < W_) ? 1.f : 0.f;                        \
    const float vx1 = (x1 >= 0 && x1 < W_) ? 1.f : 0.f;                        \
    cw0 = (1.f - wy) * (1.f - wx) * vy0 * vx0;                                 \
    cw1 = (1.f - wy) * wx * vy0 * vx1;                                         \
    cw2 = wy * (1.f - wx) * vy1 * vx0;                                         \
    cw3 = wy * wx * vy1 * vx1;                                                 \
    const int cy0 = min(max(y0, 0), H_ - 1), cy1 = min(max(y1, 0), H_ - 1);    \
    const int cx0 = min(max(x0, 0), W_ - 1), cx1 = min(max(x1, 0), W_ - 1);    \
    cb0 = ((n * H_ + cy0) * W_ + cx0) * C_;                                    \
    cb1 = ((n * H_ + cy0) * W_ + cx1) * C_;                                    \
    cb2 = ((n * H_ + cy1) * W_ + cx0) * C_;                                    \
    cb3 = ((n * H_ + cy1) * W_ + cx1) * C_;                                    \
  }

#define LOAD_CORNERS()                                                         \
  {                                                                            \
    const int cc = cg * 16;                                                    \
    u0[0] = *(const us8*)(xt + cb0 + cc); u1[0] = *(const us8*)(xt + cb0 + cc + 8); \
    u0[1] = *(const us8*)(xt + cb1 + cc); u1[1] = *(const us8*)(xt + cb1 + cc + 8); \
    u0[2] = *(const us8*)(xt + cb2 + cc); u1[2] = *(const us8*)(xt + cb2 + cc + 8); \
    u0[3] = *(const us8*)(xt + cb3 + cc); u1[3] = *(const us8*)(xt + cb3 + cc + 8); \
  }

  PREP(0);
  LOAD_CORNERS();
  for (int tap = 0; tap < 9; tap++) {
    unsigned short* __restrict__ asb = As[tap & 1];
    // lerp into As[buf] (swizzled slots: slot = (q&24)|((q^row)&7), q=chunk)
    {
      us8 r0, r1;
#pragma unroll
      for (int e = 0; e < 8; e++) {
        r0[e] = f2bf(cw0 * bf2f(u0[0][e]) + cw1 * bf2f(u0[1][e]) +
                     cw2 * bf2f(u0[2][e]) + cw3 * bf2f(u0[3][e]));
        r1[e] = f2bf(cw0 * bf2f(u1[0][e]) + cw1 * bf2f(u1[1][e]) +
                     cw2 * bf2f(u1[2][e]) + cw3 * bf2f(u1[3][e]));
      }
      const int q0 = cg * 2, q1 = cg * 2 + 1;
      const int s0 = (q0 & 24) | ((q0 ^ sr) & 7);
      const int s1 = (q1 & 24) | ((q1 ^ sr) & 7);
      *(us8*)(void*)&asb[sr * 256 + s0 * 8] = r0;
      *(us8*)(void*)&asb[sr * 256 + s1 * 8] = r1;
    }
    __syncthreads();  // lgkm-only drain: corners consumed, no DMA outstanding

    // B fragment base for this tap (global, fragment-order, L2-resident)
    const unsigned short* wfTap = Wfrag + (size_t)(tap * 8) * 8192 + (wave * 4) * 512 + lane * 8;
    bf16x8 bv[4];
#pragma unroll
    for (int ot = 0; ot < 4; ot++) bv[ot] = *(const bf16x8*)(const void*)(wfTap + ot * 512);

    if (tap < 8) {         // corner prefetch AFTER bv0 issue: in-order vmcnt
      PREP(tap + 1);       // never couples corners into the MFMA chain
      LOAD_CORNERS();
    }

#pragma unroll
    for (int ks = 0; ks < 8; ks++) {
      const int q = ks * 4 + quad;
      const int slot = (q & 24) | ((q ^ row) & 7);
      const bf16x8 av = *(const bf16x8*)(const void*)&asb[row * 256 + slot * 8];
      bf16x8 bn[4];
      if (ks < 7) {
        const unsigned short* wfn = wfTap + (size_t)(ks + 1) * 8192;
#pragma unroll
        for (int ot = 0; ot < 4; ot++) bn[ot] = *(const bf16x8*)(const void*)(wfn + ot * 512);
      }
#pragma unroll
      for (int ot = 0; ot < 4; ot++)
        acc[ot] = __builtin_amdgcn_mfma_f32_16x16x32_bf16(av, bv[ot], acc[ot], 0, 0, 0);
      if (ks < 7) {
#pragma unroll
        for (int ot = 0; ot < 4; ot++) bv[ot] = bn[ot];
      }
    }
    __syncthreads();  // protect As[buf] rewrite two taps later
  }

  // ---- Epilogue: BN + residual + ReLU, float4 rows ----
  const int hwb = m0 - n * HW_ + quad * 4;
#pragma unroll
  for (int ot = 0; ot < 4; ot++) {
    const int o = wave * 64 + ot * 16 + row;
    const float sc = rsqrtf(var[o] + 1e-5f) * gamma[o];
    const float bi = beta[o] - mean[o] * sc;
    const size_t obase = (size_t)(n * O_ + o) * HW_ + hwb;
    const f32x4 rv = *(const f32x4*)(xres + obase);
    f32x4 ov;
#pragma unroll
    for (int r = 0; r < 4; r++) ov[r] = fmaxf(acc[ot][r] * sc + bi + rv[r], 0.f);
    *(f32x4*)(out + obase) = ov;
  }
}

extern "C" void kernel_launch(void* const* d_in, const int* in_sizes, int n_in,
                              void* d_out, int out_size, void* d_ws, size_t ws_size,
                              hipStream_t stream) {
  const float* x     = (const float*)d_in[0];
  const float* w_tm  = (const float*)d_in[2];
  const float* b_tm  = (const float*)d_in[3];
  const float* w_tr  = (const float*)d_in[4];
  const float* b_tr  = (const float*)d_in[5];
  const float* w_df  = (const float*)d_in[6];
  const float* gamma = (const float*)d_in[7];
  const float* beta  = (const float*)d_in[8];
  const float* mean  = (const float*)d_in[9];
  const float* var   = (const float*)d_in[10];
  float* out = (float*)d_out;

  char* ws = (char*)d_ws;
  unsigned short* xt    = (unsigned short*)(ws);                       //  9,437,184 B
  unsigned short* wfrag = (unsigned short*)(ws + 9437184);             //  1,179,648 B
  unsigned short* w6p   = (unsigned short*)(ws + 9437184 + 1179648);   //     73,728 B

  k_pre<<<720, 256, 0, stream>>>(x, w_df, w_tm, w_tr, xt, wfrag, w6p);
  k_fused<<<1152, 256, 0, stream>>>(xt, wfrag, w6p, b_tm, b_tr, x,
                                    gamma, beta, mean, var, out);
}